// Round 5
// baseline (437.300 us; speedup 1.0000x reference)
//
#include <hip/hip_runtime.h>

// MPS chain contraction, MI355X/gfx950. N=1024 sites, B=256, D=16, d=2, C=10.
//
// out[b,o] = e0^T (prod_{n<512} A_n,b) Aout[o] (prod_{n>=512} A_n,b) e0,
//   A_n,b = x[n,b,0]*T0(n) + x[n,b,1]*T1(n).
//
// Round-5: fuse combine into the chain kernel (last-block-per-batch election,
// device-scope atomics + threadfence, hipCUB-style). Graph nodes: 3 -> 2.
// Profile evidence (r3/r4): one 256-MiB ws-poison fill (~41 us) dominates the
// top-5; kernel work models at ~12 us but non-fill time is ~46 us -> suspect
// per-node dispatch/serialization overhead; reduce node count.
//
// Chain (unchanged from r4): transposed chain on the MFMA pipe. Carry W=V^T;
// one site = mfma(A=[T0^T|T1^T] static prepacked, B=[x0*W;x1*W] built from the
// previous D-frag via 8 ds_bpermute quad-exchange). In-block 2-level tree
// folds 4 segment products -> 1 group matrix (order-preserving, transposed).
// Elected block: 3-level MFMA tree over 16 group mats + bilinear with Aout.
//
// bf16 note: half-chain magnitudes ~e^-148 (below all fp32/bf16 normals), so
// ref and kernel outputs are both exactly 0; the chain itself is computed
// faithfully (ordered, associativity-equivalent tree).

#define BATCH  256
#define NCLS   10
#define NSITES 1024
#define NGRP   16          // 16 groups x 4 segments = 64 segments
#define SEGLEN 16          // sites per segment

typedef __attribute__((ext_vector_type(8))) short short8;    // bf16x8 frag
typedef __attribute__((ext_vector_type(4))) float f32x4;     // fp32 accum
typedef __attribute__((ext_vector_type(4))) unsigned short us4;

static __device__ __forceinline__ unsigned short bf16tr(float f) {
    return (unsigned short)(__builtin_bit_cast(unsigned, f) >> 16);
}
static __device__ __forceinline__ unsigned short bf16rne(float f) {
    unsigned u = __builtin_bit_cast(unsigned, f);
    u += 0x7FFFu + ((u >> 16) & 1u);
    return (unsigned short)(u >> 16);
}
static __device__ __forceinline__ float bf16tof(unsigned short h) {
    return __builtin_bit_cast(float, (unsigned)h << 16);
}

// ---- K0: pack tensor (N,16,16,2) fp32 -> Ta (N, m, k) bf16, k in [0,32):
//   Ta[n][m][k] = [T0^T | T1^T][m][k] = tensor[n][k&15][m][k>>4].
//   Also zeroes the per-batch election counters (d_ws is poisoned each call).
__global__ __launch_bounds__(256) void ta_pack_kernel(
    const float* __restrict__ tensor, unsigned short* __restrict__ Ta,
    int* __restrict__ cnt)
{
    __shared__ float s[512];
    const int n = blockIdx.x, t = threadIdx.x;
    if (n == 0) cnt[t] = 0;                 // 256 counters, one per batch
    *(float2*)(s + 2 * t) = *(const float2*)(tensor + (size_t)n * 512 + 2 * t);
    __syncthreads();
    const int o0 = 2 * t, m = o0 >> 5, k0 = o0 & 31;   // k0 even, k0+1 same m
    const float v0 = s[(k0 & 15) * 32 + m * 2 + (k0 >> 4)];
    const int k1 = k0 + 1;
    const float v1 = s[(k1 & 15) * 32 + m * 2 + (k1 >> 4)];
    const unsigned pk = (unsigned)bf16rne(v0) | ((unsigned)bf16rne(v1) << 16);
    ((unsigned*)Ta)[(size_t)n * 256 + t] = pk;
}

// ---- K1: per-wave transposed segment chain + in-block 4->1 tree +
//          last-block-per-batch 16->2 tree + bilinear (fused combine).
__global__ __launch_bounds__(256) void chain_kernel(
    const float* __restrict__ x,            // (N, B, 2)
    const unsigned short* __restrict__ Ta,  // (N, 16, 32) bf16
    unsigned short* __restrict__ M2,        // (B, NGRP) mats, CM of R^T
    int* __restrict__ cnt,                  // (B) election counters
    const float* __restrict__ Aout,         // (C, 16, 16) fp32
    float* __restrict__ out)                // (B, C)
{
    __shared__ unsigned short rm[16 * 256]; // RM: rm[p*256 + row*16 + col]
    __shared__ unsigned short cm[16 * 256]; // CM: cm[p*256 + col*16 + row]
    __shared__ int elect;
    const int t = threadIdx.x, wave = t >> 6, lane = t & 63;
    const int quad = lane >> 4, l15 = lane & 15;
    const int b = blockIdx.x >> 4, g = blockIdx.x & 15;
    const int seg = g * 4 + wave, n0 = seg * SEGLEN;

    // bpermute byte indices for the quad-exchange (W[row][n] lives in lane
    // (row>>2)*16 + n, reg row&3):
    const int qm = quad & 1;
    const int bidx0 = (32 * qm + l15) * 4;   // source quad 2*qm   -> b[j=0..3]
    const int bidx1 = bidx0 + 64;            // source quad 2*qm+1 -> b[j=4..7]

    // W = V^T as D-frag; init I.
    f32x4 d;
#pragma unroll
    for (int r = 0; r < 4; ++r) d[r] = (quad * 4 + r == l15) ? 1.0f : 0.0f;

    const float2* __restrict__ xp = (const float2*)x;

#pragma unroll 4
    for (int s = 0; s < SEGLEN; ++s) {
        const int n = n0 + s;
        const float2 xv = xp[(size_t)n * BATCH + b];          // wave-uniform
        const float xs = (quad < 2) ? xv.x : xv.y;
        // static A-frag: a[j] = Ta[n][l15][quad*8+j]
        const short8 af = *(const short8*)(Ta + (size_t)n * 512 + l15 * 32 + quad * 8);
        // B-frag: b[j] = xs * W[(quad&1)*8 + j][l15] via quad-exchange
        float w[8];
#pragma unroll
        for (int r = 0; r < 4; ++r) {
            w[r]     = __builtin_bit_cast(float,
                        __builtin_amdgcn_ds_bpermute(bidx0, __builtin_bit_cast(int, d[r])));
            w[4 + r] = __builtin_bit_cast(float,
                        __builtin_amdgcn_ds_bpermute(bidx1, __builtin_bit_cast(int, d[r])));
        }
        short8 bf;
#pragma unroll
        for (int j = 0; j < 8; ++j) bf[j] = (short)bf16tr(xs * w[j]);
        f32x4 c = {0.0f, 0.0f, 0.0f, 0.0f};
        d = __builtin_amdgcn_mfma_f32_16x16x32_bf16(af, bf, c, 0, 0, 0);
    }
    // d = P^T_seg in D-layout: lane holds P^T[4*quad+r][l15].

    // ---- stage P^T -> slot `wave` (RM scatter + CM contiguous b64)
#pragma unroll
    for (int r = 0; r < 4; ++r)
        rm[wave * 256 + (quad * 4 + r) * 16 + l15] = bf16tr(d[r]);
    {
        us4 pk = {bf16tr(d[0]), bf16tr(d[1]), bf16tr(d[2]), bf16tr(d[3])};
        *(us4*)(cm + wave * 256 + l15 * 16 + quad * 4) = pk;
    }
    __syncthreads();

    const short8 z8 = {0, 0, 0, 0, 0, 0, 0, 0};

    // ---- level 1: wave w<2: Q^T_w = P^T_{2w+1} * P^T_{2w}  (K=16: quads 2,3 zero)
    short8 af1 = z8, bf1 = z8;
    if (wave < 2 && quad < 2) {
        af1 = *(const short8*)(rm + (2 * wave + 1) * 256 + l15 * 16 + quad * 8);
        bf1 = *(const short8*)(cm + (2 * wave) * 256 + l15 * 16 + quad * 8);
    }
    __syncthreads();   // all level-1 reads done before slots are overwritten
    if (wave < 2) {
        f32x4 c = {0.0f, 0.0f, 0.0f, 0.0f};
        f32x4 q = __builtin_amdgcn_mfma_f32_16x16x32_bf16(af1, bf1, c, 0, 0, 0);
#pragma unroll
        for (int r = 0; r < 4; ++r)
            rm[wave * 256 + (quad * 4 + r) * 16 + l15] = bf16tr(q[r]);
        us4 pk = {bf16tr(q[0]), bf16tr(q[1]), bf16tr(q[2]), bf16tr(q[3])};
        *(us4*)(cm + wave * 256 + l15 * 16 + quad * 4) = pk;
    }
    __syncthreads();

    // ---- level 2: wave 0: R^T = Q^T_1 * Q^T_0; store CM(R^T) to M2
    if (wave == 0) {
        short8 af2 = z8, bf2 = z8;
        if (quad < 2) {
            af2 = *(const short8*)(rm + 1 * 256 + l15 * 16 + quad * 8);
            bf2 = *(const short8*)(cm + 0 * 256 + l15 * 16 + quad * 8);
        }
        f32x4 c = {0.0f, 0.0f, 0.0f, 0.0f};
        f32x4 rr = __builtin_amdgcn_mfma_f32_16x16x32_bf16(af2, bf2, c, 0, 0, 0);
        us4 pk = {bf16tr(rr[0]), bf16tr(rr[1]), bf16tr(rr[2]), bf16tr(rr[3])};
        *(us4*)(M2 + ((size_t)b * NGRP + g) * 256 + l15 * 16 + quad * 4) = pk;
    }

    // ---- election: last block of this batch does the combine.
    __threadfence();   // release wave-0's M2 stores to device scope
    if (t == 0) elect = (atomicAdd(&cnt[b], 1) == NGRP - 1) ? 1 : 0;
    __syncthreads();
    if (!elect) return;
    __threadfence();   // acquire: all 16 blocks' M2 stores now visible

    // ---- stage 16 mats (8 KB): CM coalesced from global, RM via b16 scatter.
    const short8* __restrict__ src = (const short8*)(M2 + (size_t)b * NGRP * 256);
#pragma unroll
    for (int i2 = 0; i2 < 2; ++i2) {
        const int i = t + 256 * i2;                 // 512 short8 total
        const short8 v = src[i];
        *((short8*)cm + i) = v;
        const int mat = i >> 5, c = (i >> 1) & 15, r0 = (i & 1) * 8;
#pragma unroll
        for (int e = 0; e < 8; ++e)
            rm[mat * 256 + (r0 + e) * 16 + c] = (unsigned short)v[e];
    }
    __syncthreads();

    // ---- tree: np products per level; slot p <- slot_{2p+1} * slot_{2p}.
    for (int lvl = 0; lvl < 3; ++lvl) {
        const int np = 8 >> lvl;
        short8 afr[2], bfr[2];
        int pids[2], nmine = 0;
        for (int p = wave; p < np; p += 4) {
            short8 a = z8, bb = z8;
            if (quad < 2) {
                a  = *(const short8*)(rm + (2 * p + 1) * 256 + l15 * 16 + quad * 8);
                bb = *(const short8*)(cm + (2 * p) * 256 + l15 * 16 + quad * 8);
            }
            afr[nmine] = a; bfr[nmine] = bb; pids[nmine] = p; ++nmine;
        }
        __syncthreads();
        for (int ii = 0; ii < nmine; ++ii) {
            f32x4 c = {0.0f, 0.0f, 0.0f, 0.0f};
            f32x4 r = __builtin_amdgcn_mfma_f32_16x16x32_bf16(afr[ii], bfr[ii], c, 0, 0, 0);
            const int p = pids[ii];
#pragma unroll
            for (int rr = 0; rr < 4; ++rr)
                rm[p * 256 + (quad * 4 + rr) * 16 + l15] = bf16tr(r[rr]);
            us4 pk = {bf16tr(r[0]), bf16tr(r[1]), bf16tr(r[2]), bf16tr(r[3])};
            *(us4*)(cm + p * 256 + l15 * 16 + quad * 4) = pk;
        }
        __syncthreads();
    }

    // slot0 = L^T, slot1 = Rt^T.
    // vl[l] = L[0][l] = rm[l*16], vr[r] = Rt[r][0] = rm[256 + r].
    if (t < NCLS * 16) {
        const int o = t >> 4, r = t & 15;
        const float vr = bf16tof(rm[256 + r]);
        float s = 0.0f;
#pragma unroll
        for (int l = 0; l < 16; ++l)
            s = __builtin_fmaf(bf16tof(rm[l * 16]), Aout[((size_t)o * 16 + l) * 16 + r], s);
        s *= vr;
#pragma unroll
        for (int off = 8; off > 0; off >>= 1)
            s += __shfl_xor(s, off, 16);
        if (r == 0) out[(size_t)b * NCLS + o] = s;
    }
}

extern "C" void kernel_launch(void* const* d_in, const int* in_sizes, int n_in,
                              void* d_out, int out_size, void* d_ws, size_t ws_size,
                              hipStream_t stream)
{
    const float* x      = (const float*)d_in[0];   // 1024*256*2
    const float* tensor = (const float*)d_in[1];   // 1024*16*16*2
    const float* Aout   = (const float*)d_in[2];   // 10*16*16
    float* out = (float*)d_out;                    // 256*10

    unsigned short* Ta = (unsigned short*)d_ws;                      // 1 MB
    unsigned short* M2 = (unsigned short*)((char*)d_ws + (1 << 20)); // 2 MB
    int* cnt           = (int*)((char*)d_ws + (3 << 20));            // 1 KB

    ta_pack_kernel<<<NSITES, 256, 0, stream>>>(tensor, Ta, cnt);
    chain_kernel<<<BATCH * NGRP, 256, 0, stream>>>(x, Ta, M2, cnt, Aout, out);
}

// Round 6
// 101.821 us; speedup vs baseline: 4.2948x; 4.2948x over previous
//
#include <hip/hip_runtime.h>

// MPS chain contraction, MI355X/gfx950. N=1024 sites, B=256, D=16, d=2, C=10.
//
// out[b,o] = e0^T (prod_{n<512} A_n,b) Aout[o] (prod_{n>=512} A_n,b) e0,
//   A_n,b = x[n,b,0]*T0(n) + x[n,b,1]*T1(n).
//
// Round-6: ONE 1024-thread block per batch (256 blocks = 1/CU); no cross-
// block communication at all (r5's device-scope fences cost 430 us: each
// __threadfence -> buffer_wbl2+buffer_inv L2 flush, serialized at TCC).
//   - 16 waves x 4 interleaved chains/wave (4-way ILP) = 64 segment products
//     of 16 sites each, on the MFMA pipe (transposed chain, carry W=V^T:
//     one site = mfma(A=[T0^T|T1^T] prepacked static, B=[x0*W;x1*W] built
//     from the previous D-frag via 8 ds_bpermute quad-exchange)).
//   - 5-level in-LDS pairwise MFMA tree (order-preserving, transposed land:
//     slot p <- slot_{2p+1} * slot_{2p}) -> slot0 = L^T, slot1 = R^T.
//   - bilinear with Aout, 16-lane shuffle reduce.
//
// bf16 note: half-chain magnitudes ~e^-148 (below all fp32/bf16 normals), so
// ref and kernel outputs are both exactly 0; the chain itself is computed
// faithfully (ordered, associativity-equivalent tree).

#define BATCH  256
#define NCLS   10
#define NSITES 1024
#define NSEGB  64          // segments per batch (= per block)
#define SEGLEN 16          // sites per segment
#define NWAVE  16          // waves per block
#define CPW    4           // chains (segments) per wave, interleaved for ILP

typedef __attribute__((ext_vector_type(8))) short short8;    // bf16x8 frag
typedef __attribute__((ext_vector_type(4))) float f32x4;     // fp32 accum
typedef __attribute__((ext_vector_type(4))) unsigned short us4;

static __device__ __forceinline__ unsigned short bf16tr(float f) {
    return (unsigned short)(__builtin_bit_cast(unsigned, f) >> 16);
}
static __device__ __forceinline__ unsigned short bf16rne(float f) {
    unsigned u = __builtin_bit_cast(unsigned, f);
    u += 0x7FFFu + ((u >> 16) & 1u);
    return (unsigned short)(u >> 16);
}
static __device__ __forceinline__ float bf16tof(unsigned short h) {
    return __builtin_bit_cast(float, (unsigned)h << 16);
}

// ---- K0: pack tensor (N,16,16,2) fp32 -> Ta (N, m, k) bf16, k in [0,32):
//   Ta[n][m][k] = [T0^T | T1^T][m][k] = tensor[n][k&15][m][k>>4].
//   A-frag read in K1: lane m=l15, 8 consecutive k at quad*8 -> one b128.
__global__ __launch_bounds__(256) void ta_pack_kernel(
    const float* __restrict__ tensor, unsigned short* __restrict__ Ta)
{
    __shared__ float s[512];
    const int n = blockIdx.x, t = threadIdx.x;
    *(float2*)(s + 2 * t) = *(const float2*)(tensor + (size_t)n * 512 + 2 * t);
    __syncthreads();
    const int o0 = 2 * t, m = o0 >> 5, k0 = o0 & 31;   // k0 even, k0+1 same m
    const float v0 = s[(k0 & 15) * 32 + m * 2 + (k0 >> 4)];
    const int k1 = k0 + 1;
    const float v1 = s[(k1 & 15) * 32 + m * 2 + (k1 >> 4)];
    const unsigned pk = (unsigned)bf16rne(v0) | ((unsigned)bf16rne(v1) << 16);
    ((unsigned*)Ta)[(size_t)n * 256 + t] = pk;
}

// ---- K1: fused per-batch chain + tree + bilinear. 1024 threads, 64 KB LDS.
__global__ __launch_bounds__(1024) void chain_kernel(
    const float* __restrict__ x,            // (N, B, 2)
    const unsigned short* __restrict__ Ta,  // (N, 16, 32) bf16
    const float* __restrict__ Aout,         // (C, 16, 16) fp32
    float* __restrict__ out)                // (B, C)
{
    __shared__ unsigned short rm[NSEGB * 256]; // slot p RM: rm[p*256+row*16+col] = P^T[row][col]
    __shared__ unsigned short cm[NSEGB * 256]; // slot p CM: cm[p*256+col*16+row]
    const int t = threadIdx.x, wave = t >> 6, lane = t & 63;
    const int quad = lane >> 4, l15 = lane & 15;
    const int b = blockIdx.x;

    // bpermute byte indices for the quad-exchange (W[row][n] lives in lane
    // (row>>2)*16 + n, reg row&3):
    const int qm = quad & 1;
    const int bidx0 = (32 * qm + l15) * 4;   // source quad 2*qm   -> b[j=0..3]
    const int bidx1 = bidx0 + 64;            // source quad 2*qm+1 -> b[j=4..7]

    // CPW independent transposed chains per wave; W = V^T as D-frag, init I.
    f32x4 d[CPW];
#pragma unroll
    for (int c = 0; c < CPW; ++c)
#pragma unroll
        for (int r = 0; r < 4; ++r) d[c][r] = (quad * 4 + r == l15) ? 1.0f : 0.0f;

    const float2* __restrict__ xp = (const float2*)x;

#pragma unroll 1
    for (int s = 0; s < SEGLEN; ++s) {
#pragma unroll
        for (int c = 0; c < CPW; ++c) {
            const int n = (wave * CPW + c) * SEGLEN + s;
            const float2 xv = xp[(size_t)n * BATCH + b];      // wave-uniform
            const float xs = (quad < 2) ? xv.x : xv.y;
            // static A-frag: a[j] = Ta[n][l15][quad*8+j]
            const short8 af = *(const short8*)(Ta + (size_t)n * 512 + l15 * 32 + quad * 8);
            // B-frag: b[j] = xs * W[(quad&1)*8 + j][l15] via quad-exchange
            float w[8];
#pragma unroll
            for (int r = 0; r < 4; ++r) {
                w[r]     = __builtin_bit_cast(float,
                            __builtin_amdgcn_ds_bpermute(bidx0, __builtin_bit_cast(int, d[c][r])));
                w[4 + r] = __builtin_bit_cast(float,
                            __builtin_amdgcn_ds_bpermute(bidx1, __builtin_bit_cast(int, d[c][r])));
            }
            short8 bf;
#pragma unroll
            for (int j = 0; j < 8; ++j) bf[j] = (short)bf16tr(xs * w[j]);
            f32x4 cz = {0.0f, 0.0f, 0.0f, 0.0f};
            d[c] = __builtin_amdgcn_mfma_f32_16x16x32_bf16(af, bf, cz, 0, 0, 0);
        }
    }
    // d[c] = P^T_{seg=wave*4+c} in D-layout: lane holds P^T[4*quad+r][l15].

    // ---- stage all 64 products (RM b16 scatter + CM contiguous b64)
#pragma unroll
    for (int c = 0; c < CPW; ++c) {
        const int p = wave * CPW + c;
#pragma unroll
        for (int r = 0; r < 4; ++r)
            rm[p * 256 + (quad * 4 + r) * 16 + l15] = bf16tr(d[c][r]);
        us4 pk = {bf16tr(d[c][0]), bf16tr(d[c][1]), bf16tr(d[c][2]), bf16tr(d[c][3])};
        *(us4*)(cm + p * 256 + l15 * 16 + quad * 4) = pk;
    }
    __syncthreads();

    const short8 z8 = {0, 0, 0, 0, 0, 0, 0, 0};

    // ---- 5-level tree: level lvl has np = 32>>lvl products;
    //      slot p <- slot_{2p+1} * slot_{2p}  (transposed land, K=16).
    // After 5 levels: slot0 = L^T (segs 0..31), slot1 = R^T (segs 32..63).
    for (int lvl = 0; lvl < 5; ++lvl) {
        const int np = 32 >> lvl;
        short8 afr[2], bfr[2];
        int pids[2], nmine = 0;
        for (int p = wave; p < np; p += NWAVE) {
            short8 a = z8, bb = z8;
            if (quad < 2) {
                a  = *(const short8*)(rm + (2 * p + 1) * 256 + l15 * 16 + quad * 8);
                bb = *(const short8*)(cm + (2 * p) * 256 + l15 * 16 + quad * 8);
            }
            afr[nmine] = a; bfr[nmine] = bb; pids[nmine] = p; ++nmine;
        }
        __syncthreads();
        for (int ii = 0; ii < nmine; ++ii) {
            f32x4 cz = {0.0f, 0.0f, 0.0f, 0.0f};
            f32x4 r = __builtin_amdgcn_mfma_f32_16x16x32_bf16(afr[ii], bfr[ii], cz, 0, 0, 0);
            const int p = pids[ii];
#pragma unroll
            for (int rr = 0; rr < 4; ++rr)
                rm[p * 256 + (quad * 4 + rr) * 16 + l15] = bf16tr(r[rr]);
            us4 pk = {bf16tr(r[0]), bf16tr(r[1]), bf16tr(r[2]), bf16tr(r[3])};
            *(us4*)(cm + p * 256 + l15 * 16 + quad * 4) = pk;
        }
        __syncthreads();
    }

    // slot0 = L^T, slot1 = R^T.
    // vl[l] = L[0][l] = rm[l*16], vr[r] = R[r][0] = rm[256 + r].
    if (t < NCLS * 16) {
        const int o = t >> 4, r = t & 15;
        const float vr = bf16tof(rm[256 + r]);
        float s = 0.0f;
#pragma unroll
        for (int l = 0; l < 16; ++l)
            s = __builtin_fmaf(bf16tof(rm[l * 16]), Aout[((size_t)o * 16 + l) * 16 + r], s);
        s *= vr;
#pragma unroll
        for (int off = 8; off > 0; off >>= 1)
            s += __shfl_xor(s, off, 16);
        if (r == 0) out[(size_t)b * NCLS + o] = s;
    }
}

extern "C" void kernel_launch(void* const* d_in, const int* in_sizes, int n_in,
                              void* d_out, int out_size, void* d_ws, size_t ws_size,
                              hipStream_t stream)
{
    const float* x      = (const float*)d_in[0];   // 1024*256*2
    const float* tensor = (const float*)d_in[1];   // 1024*16*16*2
    const float* Aout   = (const float*)d_in[2];   // 10*16*16
    float* out = (float*)d_out;                    // 256*10

    unsigned short* Ta = (unsigned short*)d_ws;    // 1 MB

    ta_pack_kernel<<<NSITES, 256, 0, stream>>>(tensor, Ta);
    chain_kernel<<<BATCH, 1024, 0, stream>>>(x, Ta, Aout, out);
}